// Round 7
// baseline (336.154 us; speedup 1.0000x reference)
//
#include <hip/hip_runtime.h>
#include <hip/hip_bf16.h>
#include <math.h>

typedef __attribute__((ext_vector_type(8))) short short8;
typedef __attribute__((ext_vector_type(4))) float float4v;
typedef __attribute__((ext_vector_type(2))) unsigned int uint2v;

#define C_DIM 192
#define NHEADS 6
#define NTOK 50176

__device__ __forceinline__ float bf2f(unsigned short u){
  union { unsigned int i; float f; } x; x.i = ((unsigned int)u) << 16; return x.f;
}
__device__ __forceinline__ unsigned short f2bf(float f){
  union { float f; unsigned int i; } x; x.f = f;
  unsigned int r = x.i + 0x7fff + ((x.i >> 16) & 1);
  return (unsigned short)(r >> 16);
}
// round-to-bf16, result in top 16 bits (pre-shift)
__device__ __forceinline__ unsigned int rbf(float f){
  union { float f; unsigned int i; } x; x.f = f;
  return x.i + 0x7fff + ((x.i >> 16) & 1);
}
// pack two rounded bf16 (lo -> bits 15:0, hi -> bits 31:16) with one v_perm
__device__ __forceinline__ unsigned int pack_bf2(float lo, float hi){
  return __builtin_amdgcn_perm(rbf(hi), rbf(lo), 0x07060302);
}

// async 16B global->LDS (direct-to-shared DMA; dest = wave-uniform base + lane*16)
__device__ __forceinline__ void gload_lds16(const unsigned short* g, unsigned short* l){
  __builtin_amdgcn_global_load_lds((const __attribute__((address_space(1))) void*)g,
                                   (__attribute__((address_space(3))) void*)l, 16, 0, 0);
}

// window-layout row r -> natural token index
__device__ __forceinline__ int nat_token(int r){
  int win = r / 49, n = r - win * 49;
  int b = win >> 6, rem = win & 63;
  int hs = (rem >> 3) * 7 + n / 7;
  int ws = (rem & 7) * 7 + n % 7;
  int h = hs + 3; if (h >= 56) h -= 56;
  int w = ws + 3; if (w >= 56) w -= 56;
  return (b * 56 + h) * 56 + w;
}

// 7-op NaN-free tanh-form GELU (round-4); |err| < 6e-4
__device__ __forceinline__ float gelu_f(float v){
  float t = v * v;
  float u = fmaf(0.1029436f, t, 2.302208f);
  float e = __builtin_amdgcn_exp2f(-v * u);
  return v * __builtin_amdgcn_rcpf(1.f + e);
}

// ---------------- weight transpose + f32->bf16: in[R][C] fp32 -> out[C][R] bf16 ----------------
__global__ void transpose_kernel(const float* __restrict__ in,
                                 unsigned short* __restrict__ out, int R, int Cc){
  int idx = blockIdx.x * 256 + threadIdx.x;
  if (idx < R * Cc){ int r = idx / Cc, c = idx - r * Cc; out[(long)c * R + r] = f2bf(in[idx]); }
}

// ---------------- LN1 + shift + window partition (gather): fp32 in -> bf16 out ----------------
__global__ __launch_bounds__(256) void ln1_kernel(const float* __restrict__ x,
                                                  const float* __restrict__ w,
                                                  const float* __restrict__ b,
                                                  unsigned short* __restrict__ out){
  int wave = threadIdx.x >> 6, lane = threadIdx.x & 63;
  int r = blockIdx.x * 4 + wave;            // dest row, window layout
  int src = nat_token(r);
  const float* xp = x + (long)src * C_DIM;
  float v0 = xp[lane], v1 = xp[lane + 64], v2 = xp[lane + 128];
  float s = v0 + v1 + v2, s2 = v0*v0 + v1*v1 + v2*v2;
  for (int m = 32; m >= 1; m >>= 1){ s += __shfl_xor(s, m, 64); s2 += __shfl_xor(s2, m, 64); }
  float mean = s * (1.f/192.f);
  float var  = s2 * (1.f/192.f) - mean*mean;
  float rs = rsqrtf(var + 1e-5f);
  unsigned short* op = out + (long)r * C_DIM;
  op[lane]       = f2bf((v0-mean)*rs*w[lane]       + b[lane]);
  op[lane + 64]  = f2bf((v1-mean)*rs*w[lane + 64]  + b[lane + 64]);
  op[lane + 128] = f2bf((v2-mean)*rs*w[lane + 128] + b[lane + 128]);
}

// ---------------- MFMA window attention: 1 wave = 1 (window, head) ----------------
__global__ __launch_bounds__(256) void attn_kernel(const unsigned short* __restrict__ qkv,
                                                   unsigned short* __restrict__ o){
  __shared__ unsigned short pbuf[4][64][72];
  int wave = threadIdx.x >> 6, lane = threadIdx.x & 63;
  int quad = lane >> 4, l16 = lane & 15;
  int wid = blockIdx.x * 4 + wave;
  int win = wid / NHEADS, head = wid - win * NHEADS;
  const unsigned short* qp = qkv + (long)win * 49 * 576 + head * 32;
  const unsigned short* kp = qp + 192;
  const unsigned short* vp = qp + 384;

  // ---- QK^T ----
  short8 qa[4], kb[4];
  #pragma unroll
  for (int mi = 0; mi < 4; mi++){
    int m = mi * 16 + l16; if (m > 48) m = 48;
    qa[mi] = *(const short8*)&qp[(long)m * 576 + quad * 8];
  }
  #pragma unroll
  for (int ni = 0; ni < 4; ni++){
    int n = ni * 16 + l16; if (n > 48) n = 48;
    kb[ni] = *(const short8*)&kp[(long)n * 576 + quad * 8];
  }
  float4v S[4][4];
  #pragma unroll
  for (int mi = 0; mi < 4; mi++)
    #pragma unroll
    for (int ni = 0; ni < 4; ni++) S[mi][ni] = (float4v)0.f;
  #pragma unroll
  for (int mi = 0; mi < 4; mi++)
    #pragma unroll
    for (int ni = 0; ni < 4; ni++)
      S[mi][ni] = __builtin_amdgcn_mfma_f32_16x16x32_bf16(qa[mi], kb[ni], S[mi][ni], 0, 0, 0);

  // ---- softmax + P to LDS ----
  #pragma unroll
  for (int mi = 0; mi < 4; mi++){
    #pragma unroll
    for (int r = 0; r < 4; r++){
      float e[4];
      float sum = 0.f;
      #pragma unroll
      for (int ni = 0; ni < 4; ni++){
        int n = ni * 16 + l16;
        float s = S[mi][ni][r] * 0.17677669529663687f;
        s = fminf(s, 80.f);
        float ev = (n <= 48) ? __expf(s) : 0.f;
        e[ni] = ev; sum += ev;
      }
      sum += __shfl_xor(sum, 1, 64);
      sum += __shfl_xor(sum, 2, 64);
      sum += __shfl_xor(sum, 4, 64);
      sum += __shfl_xor(sum, 8, 64);
      float inv = 1.f / sum;
      int m = mi * 16 + quad * 4 + r;
      #pragma unroll
      for (int ni = 0; ni < 4; ni++)
        pbuf[wave][m][ni * 16 + l16] = f2bf(e[ni] * inv);
    }
  }
  __syncthreads();

  // ---- V^T fragments ----
  short8 vb[2][2];
  #pragma unroll
  for (int kk2 = 0; kk2 < 2; kk2++){
    #pragma unroll
    for (int ni = 0; ni < 2; ni++){
      union { unsigned short us[8]; short8 v8; } u;
      #pragma unroll
      for (int j = 0; j < 8; j++){
        int k = kk2 * 32 + quad * 8 + j; if (k > 48) k = 48;
        u.us[j] = vp[(long)k * 576 + ni * 16 + l16];
      }
      vb[kk2][ni] = u.v8;
    }
  }

  // ---- PV ----
  float4v O[4][2];
  #pragma unroll
  for (int mi = 0; mi < 4; mi++)
    #pragma unroll
    for (int ni = 0; ni < 2; ni++) O[mi][ni] = (float4v)0.f;
  #pragma unroll
  for (int kk2 = 0; kk2 < 2; kk2++){
    short8 pa[4];
    #pragma unroll
    for (int mi = 0; mi < 4; mi++)
      pa[mi] = *(const short8*)&pbuf[wave][mi * 16 + l16][kk2 * 32 + quad * 8];
    #pragma unroll
    for (int mi = 0; mi < 4; mi++)
      #pragma unroll
      for (int ni = 0; ni < 2; ni++)
        O[mi][ni] = __builtin_amdgcn_mfma_f32_16x16x32_bf16(pa[mi], vb[kk2][ni], O[mi][ni], 0, 0, 0);
  }

  // ---- write O ----
  #pragma unroll
  for (int mi = 0; mi < 4; mi++){
    int m0 = mi * 16 + quad * 4;
    #pragma unroll
    for (int r = 0; r < 4; r++){
      if (m0 + r <= 48){
        #pragma unroll
        for (int ni = 0; ni < 2; ni++)
          o[((long)win * 49 + m0 + r) * C_DIM + head * 32 + ni * 16 + l16] = f2bf(O[mi][ni][r]);
      }
    }
  }
}

// ---------------- qkv GEMM (round-4 proven: single-buffer, transposed-acc epi) ----------------
__global__ __launch_bounds__(256) void gemm_kernel(const unsigned short* __restrict__ A,
                                                   const unsigned short* __restrict__ Bt,
                                                   const float* __restrict__ bias,
                                                   unsigned short* __restrict__ Cout,
                                                   int N, int K){
  __shared__ unsigned short As[128 * 64];
  __shared__ unsigned short Bs[64 * 64];
  int tid = threadIdx.x;
  int wave = tid >> 6, lane = tid & 63, quad = lane >> 4, l16 = lane & 15;
  int wm = (wave >> 1) * 64, wn = (wave & 1) * 32;
  int lrow = lane >> 3, lg = lane & 7;
  int gcol = (lg ^ lrow) * 8;
  float4v acc[4][2];
  #pragma unroll
  for (int i = 0; i < 4; i++)
    #pragma unroll
    for (int jj = 0; jj < 2; jj++) acc[i][jj] = (float4v)0.f;

  long arow0 = (long)blockIdx.x * 128;
  long brow0 = (long)blockIdx.y * 64;
  int sw = (l16 & 7);

  for (int k0 = 0; k0 < K; k0 += 64){
    #pragma unroll
    for (int t = 0; t < 4; t++){
      int ci = wave + 4 * t;
      gload_lds16(&A[(arow0 + ci * 8 + lrow) * (long)K + k0 + gcol], &As[ci * 512]);
    }
    #pragma unroll
    for (int t = 0; t < 2; t++){
      int ci = wave + 4 * t;
      gload_lds16(&Bt[(brow0 + ci * 8 + lrow) * (long)K + k0 + gcol], &Bs[ci * 512]);
    }
    __syncthreads();
    #pragma unroll
    for (int kk8 = 0; kk8 < 8; kk8 += 4){
      short8 a[4], b[2];
      #pragma unroll
      for (int mi = 0; mi < 4; mi++)
        a[mi] = *(const short8*)&As[(wm + mi*16 + l16) * 64 + ((quad + kk8) ^ sw) * 8];
      #pragma unroll
      for (int ni = 0; ni < 2; ni++)
        b[ni] = *(const short8*)&Bs[(wn + ni*16 + l16) * 64 + ((quad + kk8) ^ sw) * 8];
      #pragma unroll
      for (int mi = 0; mi < 4; mi++)
        #pragma unroll
        for (int ni = 0; ni < 2; ni++)
          acc[mi][ni] = __builtin_amdgcn_mfma_f32_16x16x32_bf16(b[ni], a[mi], acc[mi][ni], 0, 0, 0);
    }
    __syncthreads();
  }

  float4v bias4[2];
  #pragma unroll
  for (int ni = 0; ni < 2; ni++)
    bias4[ni] = *(const float4v*)&bias[brow0 + wn + ni*16 + quad*4];

  #pragma unroll
  for (int mi = 0; mi < 4; mi++){
    long r = arow0 + wm + mi*16 + l16;
    #pragma unroll
    for (int ni = 0; ni < 2; ni++){
      long c0 = brow0 + wn + ni*16 + quad*4;
      float4v v = acc[mi][ni] + bias4[ni];
      uint2v pp;
      pp[0] = pack_bf2(v[0], v[1]);
      pp[1] = pack_bf2(v[2], v[3]);
      *(uint2v*)&Cout[r * N + c0] = pp;
    }
  }
}

// ---------------- fused proj + residual + LN2 (round-6 proven) ----------------
__global__ __launch_bounds__(512, 4) void proj_ln2_kernel(const unsigned short* __restrict__ A,
                                                          const unsigned short* __restrict__ Bt,
                                                          const float* __restrict__ bias,
                                                          const float* __restrict__ x,
                                                          float* __restrict__ y,
                                                          const float* __restrict__ lnw,
                                                          const float* __restrict__ lnb,
                                                          unsigned short* __restrict__ hn){
  __shared__ unsigned short As[64 * 64];     // 8 KB
  __shared__ unsigned short Bs[192 * 64];    // 24 KB
  __shared__ float lnred[2][2][16][4][2];    // 2 KB
  int tid = threadIdx.x;
  int wave = tid >> 6, lane = tid & 63, quad = lane >> 4, l16 = lane & 15;
  int wr = wave >> 2, wc = wave & 3;
  int lrow = lane >> 3, lg = lane & 7;
  int gcol = (lg ^ lrow) * 8;
  int sw = (l16 & 7);
  long arow0 = (long)blockIdx.x * 64;

  float4v acc[2][3];
  #pragma unroll
  for (int i = 0; i < 2; i++)
    #pragma unroll
    for (int j = 0; j < 3; j++) acc[i][j] = (float4v)0.f;

  for (int k0 = 0; k0 < 192; k0 += 64){
    #pragma unroll
    for (int t = 0; t < 4; t++){
      int i = wave + 8 * t;
      if (i < 8){
        gload_lds16(&A[(arow0 + i * 8 + lrow) * 192 + k0 + gcol], &As[i * 512]);
      } else {
        int ci = i - 8;
        gload_lds16(&Bt[(ci * 8 + lrow) * 192 + k0 + gcol], &Bs[ci * 512]);
      }
    }
    __syncthreads();
    #pragma unroll
    for (int kk8 = 0; kk8 < 8; kk8 += 4){
      short8 a[2], b[3];
      #pragma unroll
      for (int mi = 0; mi < 2; mi++)
        a[mi] = *(const short8*)&As[(wr*32 + mi*16 + l16) * 64 + ((quad + kk8) ^ sw) * 8];
      #pragma unroll
      for (int ni = 0; ni < 3; ni++)
        b[ni] = *(const short8*)&Bs[(wc*48 + ni*16 + l16) * 64 + ((quad + kk8) ^ sw) * 8];
      #pragma unroll
      for (int mi = 0; mi < 2; mi++)
        #pragma unroll
        for (int ni = 0; ni < 3; ni++)
          acc[mi][ni] = __builtin_amdgcn_mfma_f32_16x16x32_bf16(b[ni], a[mi], acc[mi][ni], 0, 0, 0);
    }
    if (k0 < 128) __syncthreads();
  }

  float4v bias4[3];
  #pragma unroll
  for (int ni = 0; ni < 3; ni++)
    bias4[ni] = *(const float4v*)&bias[wc*48 + ni*16 + quad*4];

  #pragma unroll
  for (int mi = 0; mi < 2; mi++){
    long rwin = arow0 + wr*32 + mi*16 + l16;
    long t = nat_token((int)rwin);
    float s = 0.f, s2 = 0.f;
    #pragma unroll
    for (int ni = 0; ni < 3; ni++){
      long idx = t * C_DIM + wc*48 + ni*16 + quad*4;
      float4v xr = *(const float4v*)&x[idx];
      float4v v = acc[mi][ni] + bias4[ni] + xr;
      *(float4v*)&y[idx] = v;
      acc[mi][ni] = v;
      #pragma unroll
      for (int e = 0; e < 4; e++){ s += v[e]; s2 += v[e]*v[e]; }
    }
    s  += __shfl_xor(s, 16, 64);  s  += __shfl_xor(s, 32, 64);
    s2 += __shfl_xor(s2, 16, 64); s2 += __shfl_xor(s2, 32, 64);
    if (quad == 0){ lnred[wr][mi][l16][wc][0] = s; lnred[wr][mi][l16][wc][1] = s2; }
  }
  __syncthreads();

  #pragma unroll
  for (int mi = 0; mi < 2; mi++){
    long rwin = arow0 + wr*32 + mi*16 + l16;
    float S = 0.f, S2 = 0.f;
    #pragma unroll
    for (int w = 0; w < 4; w++){ S += lnred[wr][mi][l16][w][0]; S2 += lnred[wr][mi][l16][w][1]; }
    float mean = S * (1.f/192.f);
    float var  = S2 * (1.f/192.f) - mean*mean;
    float rs = rsqrtf(var + 1e-5f);
    #pragma unroll
    for (int ni = 0; ni < 3; ni++){
      int c0 = wc*48 + ni*16 + quad*4;
      float4v w4 = *(const float4v*)&lnw[c0];
      float4v b4 = *(const float4v*)&lnb[c0];
      float4v v = acc[mi][ni];
      float g0 = (v[0]-mean)*rs*w4[0] + b4[0];
      float g1 = (v[1]-mean)*rs*w4[1] + b4[1];
      float g2 = (v[2]-mean)*rs*w4[2] + b4[2];
      float g3 = (v[3]-mean)*rs*w4[3] + b4[3];
      uint2v pp;
      pp[0] = pack_bf2(g0, g1);
      pp[1] = pack_bf2(g2, g3);
      *(uint2v*)&hn[rwin * C_DIM + c0] = pp;   // window layout, in-place over obuf
    }
  }
}

// ---------------- fused MLP v3: y += gelu(hn @ w1 + b1) @ w2 + b2 ----------------
// KEY vs v1/v2 failures: weight fragments stream PER-LANE from L2 (w1t+w2t = 590 KB,
// L2-resident) -- no weight staging, no drain-after-issue, only 2 barriers per chunk
// (both protecting the 9KB Hs roundtrip). hn A-tile staged ONCE (proven 3-plane swizzle).
// Block = 64 rows, 4 waves = (M-group: rows (wave>>1)*32..+32) x (N-half: wave&1).
// Loop j over 12 chunks of 64 h-cols:
//   GEMM1 (24 MFMA/wave): acc1[2][2] = As x w1-frags(L2);  wave N-half = (wave&1)*32 of chunk
//   gelu+pack -> Hs[64][72]; barrier
//   GEMM2 (24 MFMA/wave): acc2[2][6] += Hs x w2-frags(L2); wave N-range = (wave&1)*96 of 192
//   barrier (Hs consumed)
// Epilogue: y[nat(row)] float4 RMW. LDS 33.8 KB -> 4 blocks/CU; ~112 VGPR.
// Eliminates the 154 MB h round-trip (77 write + 77 read) = ~70 us at the observed 2.2 TB/s.
__global__ __launch_bounds__(256, 4) void fused_mlp_kernel(const unsigned short* __restrict__ hn,
                                                           const unsigned short* __restrict__ w1t,
                                                           const float* __restrict__ b1,
                                                           const unsigned short* __restrict__ w2t,
                                                           const float* __restrict__ b2,
                                                           float* __restrict__ y){
  __shared__ __attribute__((aligned(16))) unsigned short As[3 * 64 * 64];  // [gg][row][64]
  __shared__ __attribute__((aligned(16))) unsigned short Hs[64 * 72];      // gelu(h) chunk
  int tid = threadIdx.x;
  int wave = tid >> 6, lane = tid & 63, quad = lane >> 4, l16 = lane & 15;
  int wm = (wave >> 1) * 32;                  // M-group rows wm..wm+32 (both GEMMs)
  int wn1 = (wave & 1) * 32;                  // GEMM1 N-half within 64-chunk
  int wn2 = (wave & 1) * 96;                  // GEMM2 N-range within 192
  int lrow = lane >> 3, lg = lane & 7;
  int gcol = (lg ^ lrow) * 8;
  int sw = l16 & 7;
  long arow0 = (long)blockIdx.x * 64;

  float4v acc2[2][6];
  #pragma unroll
  for (int i = 0; i < 2; i++)
    #pragma unroll
    for (int j = 0; j < 6; j++) acc2[i][j] = (float4v)0.f;

  // ---- stage hn tile once: 64 rows x 192 = 3 planes x 8 row-chunks, 6 loads/wave ----
  #pragma unroll
  for (int t = 0; t < 6; t++){
    int i = wave + 4 * t; int gg = i >> 3, br8 = (i & 7) << 3;
    gload_lds16(&hn[(arow0 + br8 + lrow) * C_DIM + gg * 64 + gcol], &As[gg * 4096 + br8 * 64]);
  }
  __syncthreads();                            // drain A stage (once per block)

  #pragma unroll 1
  for (int j = 0; j < 12; j++){
    int c0 = j * 64;
    // ---- GEMM1: acc1[2 mi][2 ni] = A[wm..+32][0..192] x w1[c0+wn1..+32][0..192] ----
    float4v acc1[2][2];
    #pragma unroll
    for (int mi = 0; mi < 2; mi++)
      #pragma unroll
      for (int ni = 0; ni < 2; ni++) acc1[mi][ni] = (float4v)0.f;
    #pragma unroll
    for (int kk = 0; kk < 6; kk++){
      int gg = kk >> 1, xb = (kk & 1) * 4;
      short8 a[2];
      #pragma unroll
      for (int mi = 0; mi < 2; mi++)
        a[mi] = *(const short8*)&As[gg * 4096 + (wm + mi*16 + l16) * 64 + ((xb + quad) ^ sw) * 8];
      #pragma unroll
      for (int ni = 0; ni < 2; ni++){
        short8 b = *(const short8*)&w1t[(long)(c0 + wn1 + ni*16 + l16) * 192 + kk*32 + quad*8];
        #pragma unroll
        for (int mi = 0; mi < 2; mi++)
          acc1[mi][ni] = __builtin_amdgcn_mfma_f32_16x16x32_bf16(b, a[mi], acc1[mi][ni], 0, 0, 0);
      }
    }
    // ---- bias + gelu + pack -> Hs (thread: row = wm+mi*16+l16, 4 cols = wn1+ni*16+quad*4) ----
    #pragma unroll
    for (int ni = 0; ni < 2; ni++){
      float4v b14 = *(const float4v*)&b1[c0 + wn1 + ni*16 + quad*4];
      #pragma unroll
      for (int mi = 0; mi < 2; mi++){
        float4v v = acc1[mi][ni] + b14;
        #pragma unroll
        for (int e = 0; e < 4; e++) v[e] = gelu_f(v[e]);
        uint2v pp;
        pp[0] = pack_bf2(v[0], v[1]);
        pp[1] = pack_bf2(v[2], v[3]);
        *(uint2v*)&Hs[(wm + mi*16 + l16) * 72 + wn1 + ni*16 + quad*4] = pp;
      }
    }
    __syncthreads();                          // Hs complete (cross-wave k-columns)

    // ---- GEMM2: acc2[2 mi][6 ni] += Hs[wm..+32][0..64] x w2[wn2..+96][c0..+64] ----
    #pragma unroll
    for (int kk2 = 0; kk2 < 2; kk2++){
      short8 pa[2];
      #pragma unroll
      for (int mi = 0; mi < 2; mi++)
        pa[mi] = *(const short8*)&Hs[(wm + mi*16 + l16) * 72 + kk2*32 + quad*8];
      #pragma unroll
      for (int ni = 0; ni < 6; ni++){
        short8 b = *(const short8*)&w2t[(long)(wn2 + ni*16 + l16) * 768 + c0 + kk2*32 + quad*8];
        #pragma unroll
        for (int mi = 0; mi < 2; mi++)
          acc2[mi][ni] = __builtin_amdgcn_mfma_f32_16x16x32_bf16(b, pa[mi], acc2[mi][ni], 0, 0, 0);
      }
    }
    __syncthreads();                          // Hs consumed; safe to overwrite next j
  }

  // ---- epilogue: y[nat(row)] += acc2 + b2 (float4 RMW; one output owner per element) ----
  float4v b24[6];
  #pragma unroll
  for (int ni = 0; ni < 6; ni++)
    b24[ni] = *(const float4v*)&b2[wn2 + ni*16 + quad*4];

  #pragma unroll
  for (int mi = 0; mi < 2; mi++){
    int row = (int)(arow0 + wm + mi*16 + l16);
    long t = nat_token(row);
    #pragma unroll
    for (int ni = 0; ni < 6; ni++){
      long idx = t * C_DIM + wn2 + ni*16 + quad*4;
      float4v xr = *(const float4v*)&y[idx];
      *(float4v*)&y[idx] = xr + acc2[mi][ni] + b24[ni];
    }
  }
}

extern "C" void kernel_launch(void* const* d_in, const int* in_sizes, int n_in,
                              void* d_out, int out_size, void* d_ws, size_t ws_size,
                              hipStream_t stream){
  const float* x      = (const float*)d_in[0];
  const float* ln1_w  = (const float*)d_in[1];
  const float* ln1_b  = (const float*)d_in[2];
  const float* qkv_w  = (const float*)d_in[3];
  const float* qkv_b  = (const float*)d_in[4];
  const float* proj_w = (const float*)d_in[5];
  const float* proj_b = (const float*)d_in[6];
  const float* ln2_w  = (const float*)d_in[7];
  const float* ln2_b  = (const float*)d_in[8];
  const float* mlp_w1 = (const float*)d_in[9];
  const float* mlp_b1 = (const float*)d_in[10];
  const float* mlp_w2 = (const float*)d_in[11];
  const float* mlp_b2 = (const float*)d_in[12];
  float* out = (float*)d_out;   // fp32 output; hosts fp32 residual y between proj and MLP

  // --- aliased workspace, all internal buffers bf16 ---
  char* ws = (char*)d_ws;
  unsigned short* qkv_wt = (unsigned short*)(ws);               // [576][192]
  unsigned short* proj_wt= (unsigned short*)(ws + 221184);      // [192][192]
  unsigned short* w1t    = (unsigned short*)(ws + 294912);      // [768][192]
  unsigned short* w2t    = (unsigned short*)(ws + 589824);      // [192][768]
  unsigned short* R1     = (unsigned short*)(ws + 884736);      // 50176x192 bf16
  unsigned short* R0     = (unsigned short*)(ws + 20152320);    // 50176x576 bf16

  unsigned short* xw   = R1;    // LN1'd, window layout
  unsigned short* obuf = R1;    // attention output, window layout
  unsigned short* hn   = R1;    // LN2'd, WINDOW layout (in-place over obuf)
  unsigned short* qkv  = R0;

  transpose_kernel<<<(110592 + 255) / 256, 256, 0, stream>>>(qkv_w, qkv_wt, 192, 576);
  transpose_kernel<<<(36864  + 255) / 256, 256, 0, stream>>>(proj_w, proj_wt, 192, 192);
  transpose_kernel<<<(147456 + 255) / 256, 256, 0, stream>>>(mlp_w1, w1t, 192, 768);
  transpose_kernel<<<(147456 + 255) / 256, 256, 0, stream>>>(mlp_w2, w2t, 768, 192);

  ln1_kernel<<<NTOK / 4, 256, 0, stream>>>(x, ln1_w, ln1_b, xw);
  gemm_kernel<<<dim3(392, 9), 256, 0, stream>>>(xw, qkv_wt, qkv_b, qkv, 576, 192);
  attn_kernel<<<(NTOK / 49) * NHEADS / 4, 256, 0, stream>>>(qkv, obuf);
  proj_ln2_kernel<<<NTOK / 64, 512, 0, stream>>>(obuf, proj_wt, proj_b, x, out, ln2_w, ln2_b, hn);
  fused_mlp_kernel<<<NTOK / 64, 256, 0, stream>>>(hn, w1t, mlp_b1, w2t, mlp_b2, out);
}

// Round 8
// 275.997 us; speedup vs baseline: 1.2180x; 1.2180x over previous
//
#include <hip/hip_runtime.h>
#include <hip/hip_bf16.h>
#include <math.h>

typedef __attribute__((ext_vector_type(8))) short short8;
typedef __attribute__((ext_vector_type(4))) float float4v;
typedef __attribute__((ext_vector_type(2))) unsigned int uint2v;

#define C_DIM 192
#define NHEADS 6
#define NTOK 50176

__device__ __forceinline__ float bf2f(unsigned short u){
  union { unsigned int i; float f; } x; x.i = ((unsigned int)u) << 16; return x.f;
}
__device__ __forceinline__ unsigned short f2bf(float f){
  union { float f; unsigned int i; } x; x.f = f;
  unsigned int r = x.i + 0x7fff + ((x.i >> 16) & 1);
  return (unsigned short)(r >> 16);
}
// round-to-bf16, result in top 16 bits (pre-shift)
__device__ __forceinline__ unsigned int rbf(float f){
  union { float f; unsigned int i; } x; x.f = f;
  return x.i + 0x7fff + ((x.i >> 16) & 1);
}
// pack two rounded bf16 (lo -> bits 15:0, hi -> bits 31:16) with one v_perm
__device__ __forceinline__ unsigned int pack_bf2(float lo, float hi){
  return __builtin_amdgcn_perm(rbf(hi), rbf(lo), 0x07060302);
}

// async 16B global->LDS (direct-to-shared DMA; dest = wave-uniform base + lane*16)
__device__ __forceinline__ void gload_lds16(const unsigned short* g, unsigned short* l){
  __builtin_amdgcn_global_load_lds((const __attribute__((address_space(1))) void*)g,
                                   (__attribute__((address_space(3))) void*)l, 16, 0, 0);
}

// window-layout row r -> natural token index
__device__ __forceinline__ int nat_token(int r){
  int win = r / 49, n = r - win * 49;
  int b = win >> 6, rem = win & 63;
  int hs = (rem >> 3) * 7 + n / 7;
  int ws = (rem & 7) * 7 + n % 7;
  int h = hs + 3; if (h >= 56) h -= 56;
  int w = ws + 3; if (w >= 56) w -= 56;
  return (b * 56 + h) * 56 + w;
}

// 7-op NaN-free tanh-form GELU (round-4); |err| < 6e-4
__device__ __forceinline__ float gelu_f(float v){
  float t = v * v;
  float u = fmaf(0.1029436f, t, 2.302208f);
  float e = __builtin_amdgcn_exp2f(-v * u);
  return v * __builtin_amdgcn_rcpf(1.f + e);
}

// ---------------- weight transpose + f32->bf16: in[R][C] fp32 -> out[C][R] bf16 ----------------
__global__ void transpose_kernel(const float* __restrict__ in,
                                 unsigned short* __restrict__ out, int R, int Cc){
  int idx = blockIdx.x * 256 + threadIdx.x;
  if (idx < R * Cc){ int r = idx / Cc, c = idx - r * Cc; out[(long)c * R + r] = f2bf(in[idx]); }
}

// ---------------- LN1 + shift + window partition (gather): fp32 in -> bf16 out ----------------
__global__ __launch_bounds__(256) void ln1_kernel(const float* __restrict__ x,
                                                  const float* __restrict__ w,
                                                  const float* __restrict__ b,
                                                  unsigned short* __restrict__ out){
  int wave = threadIdx.x >> 6, lane = threadIdx.x & 63;
  int r = blockIdx.x * 4 + wave;            // dest row, window layout
  int src = nat_token(r);
  const float* xp = x + (long)src * C_DIM;
  float v0 = xp[lane], v1 = xp[lane + 64], v2 = xp[lane + 128];
  float s = v0 + v1 + v2, s2 = v0*v0 + v1*v1 + v2*v2;
  for (int m = 32; m >= 1; m >>= 1){ s += __shfl_xor(s, m, 64); s2 += __shfl_xor(s2, m, 64); }
  float mean = s * (1.f/192.f);
  float var  = s2 * (1.f/192.f) - mean*mean;
  float rs = rsqrtf(var + 1e-5f);
  unsigned short* op = out + (long)r * C_DIM;
  op[lane]       = f2bf((v0-mean)*rs*w[lane]       + b[lane]);
  op[lane + 64]  = f2bf((v1-mean)*rs*w[lane + 64]  + b[lane + 64]);
  op[lane + 128] = f2bf((v2-mean)*rs*w[lane + 128] + b[lane + 128]);
}

// ---------------- fused QKV-GEMM + window attention: block = 1 window, 12 waves ----------------
// Phase 1 (GEMM, barrier-free inner): each wave owns 48 output cols of qkv[64][576].
//   A (xw window rows, 64x192) staged once via gload_lds (3-plane swizzle, proven).
//   B streamed per-lane 16B from qkv_wt (221 KB, L2-resident; re-read per window = L2 hits).
//   acc[4][3] transposed-D (row = l16, 4 cols per quad) -> bias+pack -> 8B ds_writes into
//   QKVs[64][584] (584 = 576+8 pad: row stride 1168B == 4 banks -> 2-way aliasing = free).
// ONE barrier. Phase 2 (attention): wave = (head = w>>1, row-half = w&1); the proven attn
// code verbatim with q/k/v pointers into LDS (stride 584) and per-wave P[32][72].
// Replaces qkv-GEMM (58 MB write) + attn (58 MB read): 116 MB HBM -> 0.
// LDS = 74.75 + 55.3 (A aliased under P) = 127 KB -> 1 block/CU (12 waves).
__global__ __launch_bounds__(768) void win_attn_kernel(const unsigned short* __restrict__ xw,
                                                       const unsigned short* __restrict__ qkv_wt,
                                                       const float* __restrict__ qkv_b,
                                                       unsigned short* __restrict__ o){
  __shared__ __attribute__((aligned(16))) unsigned short QKVs[64 * 584];   // 74,752 B
  __shared__ __attribute__((aligned(16))) unsigned short Ps[12][32][72];   // 55,296 B
  unsigned short* As = &Ps[0][0][0];          // A tile (24,576 B) aliased; dead before P use
  int tid = threadIdx.x;
  int wave = tid >> 6, lane = tid & 63, quad = lane >> 4, l16 = lane & 15;
  int lrow = lane >> 3, lg = lane & 7;
  int gcol = (lg ^ lrow) * 8;
  int sw = l16 & 7;
  int win = blockIdx.x;
  long arow0 = (long)win * 49;

  // ---- stage A: xw rows win*49 .. +64 (rows >=49 spill into next window / ws garbage;
  //      never read numerically: Q/K/V row accesses are clamped to <=48 below) ----
  #pragma unroll
  for (int t = 0; t < 2; t++){
    int i = wave + 12 * t;                    // 0..23 = 3 planes x 8 row-chunks
    int gg = i >> 3, br8 = (i & 7) << 3;
    gload_lds16(&xw[(arow0 + br8 + lrow) * C_DIM + gg * 64 + gcol], &As[gg * 4096 + br8 * 64]);
  }
  __syncthreads();                            // A staged

  // ---- Phase 1: GEMM qkv[64][wcol0..+48] = A x qkv_wt^T, K=192 (no barriers inside) ----
  int wcol0 = wave * 48;
  float4v acc[4][3];
  #pragma unroll
  for (int i = 0; i < 4; i++)
    #pragma unroll
    for (int j = 0; j < 3; j++) acc[i][j] = (float4v)0.f;

  #pragma unroll
  for (int kk = 0; kk < 6; kk++){
    int gg = kk >> 1, xb = (kk & 1) * 4;
    short8 a[4];
    #pragma unroll
    for (int mi = 0; mi < 4; mi++)
      a[mi] = *(const short8*)&As[gg * 4096 + (mi*16 + l16) * 64 + ((xb + quad) ^ sw) * 8];
    #pragma unroll
    for (int ni = 0; ni < 3; ni++){
      short8 b = *(const short8*)&qkv_wt[(long)(wcol0 + ni*16 + l16) * 192 + kk*32 + quad*8];
      #pragma unroll
      for (int mi = 0; mi < 4; mi++)
        acc[mi][ni] = __builtin_amdgcn_mfma_f32_16x16x32_bf16(b, a[mi], acc[mi][ni], 0, 0, 0);
    }
  }
  // bias + pack -> LDS qkv tile (thread: row = mi*16+l16, cols = wcol0+ni*16+quad*4..+3)
  #pragma unroll
  for (int ni = 0; ni < 3; ni++){
    float4v b4 = *(const float4v*)&qkv_b[wcol0 + ni*16 + quad*4];
    #pragma unroll
    for (int mi = 0; mi < 4; mi++){
      float4v v = acc[mi][ni] + b4;
      uint2v pp;
      pp[0] = pack_bf2(v[0], v[1]);
      pp[1] = pack_bf2(v[2], v[3]);
      *(uint2v*)&QKVs[(mi*16 + l16) * 584 + wcol0 + ni*16 + quad*4] = pp;
    }
  }
  __syncthreads();                            // qkv tile complete; A-region now reusable as P

  // ---- Phase 2: attention. wave -> (head, row-half) ----
  int head = wave >> 1, half = wave & 1;
  const unsigned short* qp = QKVs + head * 32;
  const unsigned short* kp = QKVs + 192 + head * 32;
  const unsigned short* vp = QKVs + 384 + head * 32;

  // QK^T (q-rows: half*32 + mi*16 + l16, clamped; k-cols full 64, clamped)
  short8 qa[2], kb[4];
  #pragma unroll
  for (int mi = 0; mi < 2; mi++){
    int m = half*32 + mi*16 + l16; if (m > 48) m = 48;
    qa[mi] = *(const short8*)&qp[m * 584 + quad * 8];
  }
  #pragma unroll
  for (int ni = 0; ni < 4; ni++){
    int n = ni*16 + l16; if (n > 48) n = 48;
    kb[ni] = *(const short8*)&kp[n * 584 + quad * 8];
  }
  float4v S[2][4];
  #pragma unroll
  for (int mi = 0; mi < 2; mi++)
    #pragma unroll
    for (int ni = 0; ni < 4; ni++) S[mi][ni] = (float4v)0.f;
  #pragma unroll
  for (int mi = 0; mi < 2; mi++)
    #pragma unroll
    for (int ni = 0; ni < 4; ni++)
      S[mi][ni] = __builtin_amdgcn_mfma_f32_16x16x32_bf16(qa[mi], kb[ni], S[mi][ni], 0, 0, 0);

  // softmax + P (wave-private: no barrier; compiler orders the LDS RAW via lgkmcnt)
  #pragma unroll
  for (int mi = 0; mi < 2; mi++){
    #pragma unroll
    for (int r = 0; r < 4; r++){
      float e[4];
      float sum = 0.f;
      #pragma unroll
      for (int ni = 0; ni < 4; ni++){
        int n = ni*16 + l16;
        float s = S[mi][ni][r] * 0.17677669529663687f;   // 1/sqrt(32)
        s = fminf(s, 80.f);
        float ev = (n <= 48) ? __expf(s) : 0.f;
        e[ni] = ev; sum += ev;
      }
      sum += __shfl_xor(sum, 1, 64);
      sum += __shfl_xor(sum, 2, 64);
      sum += __shfl_xor(sum, 4, 64);
      sum += __shfl_xor(sum, 8, 64);
      float inv = 1.f / sum;
      int m = mi*16 + quad*4 + r;              // local row 0..31
      #pragma unroll
      for (int ni = 0; ni < 4; ni++)
        Ps[wave][m][ni*16 + l16] = f2bf(e[ni] * inv);
    }
  }

  // V^T fragments (scalar LDS reads; rows k>48 clamped, P there = 0)
  short8 vb[2][2];
  #pragma unroll
  for (int kk2 = 0; kk2 < 2; kk2++){
    #pragma unroll
    for (int ni = 0; ni < 2; ni++){
      union { unsigned short us[8]; short8 v8; } u;
      #pragma unroll
      for (int j = 0; j < 8; j++){
        int k = kk2*32 + quad*8 + j; if (k > 48) k = 48;
        u.us[j] = vp[k * 584 + ni*16 + l16];
      }
      vb[kk2][ni] = u.v8;
    }
  }

  // PV
  float4v O[2][2];
  #pragma unroll
  for (int mi = 0; mi < 2; mi++)
    #pragma unroll
    for (int ni = 0; ni < 2; ni++) O[mi][ni] = (float4v)0.f;
  #pragma unroll
  for (int kk2 = 0; kk2 < 2; kk2++){
    short8 pa[2];
    #pragma unroll
    for (int mi = 0; mi < 2; mi++)
      pa[mi] = *(const short8*)&Ps[wave][mi*16 + l16][kk2*32 + quad*8];
    #pragma unroll
    for (int mi = 0; mi < 2; mi++)
      #pragma unroll
      for (int ni = 0; ni < 2; ni++)
        O[mi][ni] = __builtin_amdgcn_mfma_f32_16x16x32_bf16(pa[mi], vb[kk2][ni], O[mi][ni], 0, 0, 0);
  }

  // write O: global row = win*49 + half*32 + mi*16 + quad*4 + r (valid rows only)
  #pragma unroll
  for (int mi = 0; mi < 2; mi++){
    int m0 = half*32 + mi*16 + quad*4;
    #pragma unroll
    for (int r = 0; r < 4; r++){
      if (m0 + r <= 48){
        #pragma unroll
        for (int ni = 0; ni < 2; ni++)
          o[(arow0 + m0 + r) * C_DIM + head*32 + ni*16 + l16] = f2bf(O[mi][ni][r]);
      }
    }
  }
}

// ---------------- fused proj + residual + LN2 (round-6 proven) ----------------
__global__ __launch_bounds__(512, 4) void proj_ln2_kernel(const unsigned short* __restrict__ A,
                                                          const unsigned short* __restrict__ Bt,
                                                          const float* __restrict__ bias,
                                                          const float* __restrict__ x,
                                                          float* __restrict__ y,
                                                          const float* __restrict__ lnw,
                                                          const float* __restrict__ lnb,
                                                          unsigned short* __restrict__ hn){
  __shared__ unsigned short As[64 * 64];     // 8 KB
  __shared__ unsigned short Bs[192 * 64];    // 24 KB
  __shared__ float lnred[2][2][16][4][2];    // 2 KB
  int tid = threadIdx.x;
  int wave = tid >> 6, lane = tid & 63, quad = lane >> 4, l16 = lane & 15;
  int wr = wave >> 2, wc = wave & 3;
  int lrow = lane >> 3, lg = lane & 7;
  int gcol = (lg ^ lrow) * 8;
  int sw = (l16 & 7);
  long arow0 = (long)blockIdx.x * 64;

  float4v acc[2][3];
  #pragma unroll
  for (int i = 0; i < 2; i++)
    #pragma unroll
    for (int j = 0; j < 3; j++) acc[i][j] = (float4v)0.f;

  for (int k0 = 0; k0 < 192; k0 += 64){
    #pragma unroll
    for (int t = 0; t < 4; t++){
      int i = wave + 8 * t;
      if (i < 8){
        gload_lds16(&A[(arow0 + i * 8 + lrow) * 192 + k0 + gcol], &As[i * 512]);
      } else {
        int ci = i - 8;
        gload_lds16(&Bt[(ci * 8 + lrow) * 192 + k0 + gcol], &Bs[ci * 512]);
      }
    }
    __syncthreads();
    #pragma unroll
    for (int kk8 = 0; kk8 < 8; kk8 += 4){
      short8 a[2], b[3];
      #pragma unroll
      for (int mi = 0; mi < 2; mi++)
        a[mi] = *(const short8*)&As[(wr*32 + mi*16 + l16) * 64 + ((quad + kk8) ^ sw) * 8];
      #pragma unroll
      for (int ni = 0; ni < 3; ni++)
        b[ni] = *(const short8*)&Bs[(wc*48 + ni*16 + l16) * 64 + ((quad + kk8) ^ sw) * 8];
      #pragma unroll
      for (int mi = 0; mi < 2; mi++)
        #pragma unroll
        for (int ni = 0; ni < 3; ni++)
          acc[mi][ni] = __builtin_amdgcn_mfma_f32_16x16x32_bf16(b[ni], a[mi], acc[mi][ni], 0, 0, 0);
    }
    if (k0 < 128) __syncthreads();
  }

  float4v bias4[3];
  #pragma unroll
  for (int ni = 0; ni < 3; ni++)
    bias4[ni] = *(const float4v*)&bias[wc*48 + ni*16 + quad*4];

  #pragma unroll
  for (int mi = 0; mi < 2; mi++){
    long rwin = arow0 + wr*32 + mi*16 + l16;
    long t = nat_token((int)rwin);
    float s = 0.f, s2 = 0.f;
    #pragma unroll
    for (int ni = 0; ni < 3; ni++){
      long idx = t * C_DIM + wc*48 + ni*16 + quad*4;
      float4v xr = *(const float4v*)&x[idx];
      float4v v = acc[mi][ni] + bias4[ni] + xr;
      *(float4v*)&y[idx] = v;
      acc[mi][ni] = v;
      #pragma unroll
      for (int e = 0; e < 4; e++){ s += v[e]; s2 += v[e]*v[e]; }
    }
    s  += __shfl_xor(s, 16, 64);  s  += __shfl_xor(s, 32, 64);
    s2 += __shfl_xor(s2, 16, 64); s2 += __shfl_xor(s2, 32, 64);
    if (quad == 0){ lnred[wr][mi][l16][wc][0] = s; lnred[wr][mi][l16][wc][1] = s2; }
  }
  __syncthreads();

  #pragma unroll
  for (int mi = 0; mi < 2; mi++){
    long rwin = arow0 + wr*32 + mi*16 + l16;
    float S = 0.f, S2 = 0.f;
    #pragma unroll
    for (int w = 0; w < 4; w++){ S += lnred[wr][mi][l16][w][0]; S2 += lnred[wr][mi][l16][w][1]; }
    float mean = S * (1.f/192.f);
    float var  = S2 * (1.f/192.f) - mean*mean;
    float rs = rsqrtf(var + 1e-5f);
    #pragma unroll
    for (int ni = 0; ni < 3; ni++){
      int c0 = wc*48 + ni*16 + quad*4;
      float4v w4 = *(const float4v*)&lnw[c0];
      float4v b4 = *(const float4v*)&lnb[c0];
      float4v v = acc[mi][ni];
      float g0 = (v[0]-mean)*rs*w4[0] + b4[0];
      float g1 = (v[1]-mean)*rs*w4[1] + b4[1];
      float g2 = (v[2]-mean)*rs*w4[2] + b4[2];
      float g3 = (v[3]-mean)*rs*w4[3] + b4[3];
      uint2v pp;
      pp[0] = pack_bf2(g0, g1);
      pp[1] = pack_bf2(g2, g3);
      *(uint2v*)&hn[rwin * C_DIM + c0] = pp;   // window layout
    }
  }
}

// ---------------- 128x128 GEMM + GELU (mlp1, round-6 proven) ----------------
__global__ __launch_bounds__(256, 4) void gemm128_kernel(const unsigned short* __restrict__ A,
                                                         const unsigned short* __restrict__ Bt,
                                                         const float* __restrict__ bias,
                                                         unsigned short* __restrict__ Cout,
                                                         int N, int K){
  __shared__ unsigned short As[128 * 64];
  __shared__ unsigned short Bs[128 * 64];
  int tid = threadIdx.x;
  int wave = tid >> 6, lane = tid & 63, quad = lane >> 4, l16 = lane & 15;
  int wm = (wave >> 1) * 64, wn = (wave & 1) * 64;
  int lrow = lane >> 3, lg = lane & 7;
  int gcol = (lg ^ lrow) * 8;
  int sw = (l16 & 7);
  float4v acc[4][4];
  #pragma unroll
  for (int i = 0; i < 4; i++)
    #pragma unroll
    for (int jj = 0; jj < 4; jj++) acc[i][jj] = (float4v)0.f;

  long arow0 = (long)blockIdx.x * 128;
  long brow0 = (long)blockIdx.y * 128;

  for (int k0 = 0; k0 < K; k0 += 64){
    #pragma unroll
    for (int t = 0; t < 4; t++){
      int ci = wave + 4 * t;
      gload_lds16(&A[(arow0 + ci * 8 + lrow) * (long)K + k0 + gcol], &As[ci * 512]);
    }
    #pragma unroll
    for (int t = 0; t < 4; t++){
      int ci = wave + 4 * t;
      gload_lds16(&Bt[(brow0 + ci * 8 + lrow) * (long)K + k0 + gcol], &Bs[ci * 512]);
    }
    __syncthreads();
    #pragma unroll
    for (int kk8 = 0; kk8 < 8; kk8 += 4){
      short8 a[4], b[4];
      #pragma unroll
      for (int mi = 0; mi < 4; mi++)
        a[mi] = *(const short8*)&As[(wm + mi*16 + l16) * 64 + ((quad + kk8) ^ sw) * 8];
      #pragma unroll
      for (int ni = 0; ni < 4; ni++)
        b[ni] = *(const short8*)&Bs[(wn + ni*16 + l16) * 64 + ((quad + kk8) ^ sw) * 8];
      #pragma unroll
      for (int mi = 0; mi < 4; mi++)
        #pragma unroll
        for (int ni = 0; ni < 4; ni++)
          acc[mi][ni] = __builtin_amdgcn_mfma_f32_16x16x32_bf16(b[ni], a[mi], acc[mi][ni], 0, 0, 0);
    }
    __syncthreads();
  }

  float4v bias4[4];
  #pragma unroll
  for (int ni = 0; ni < 4; ni++)
    bias4[ni] = *(const float4v*)&bias[brow0 + wn + ni*16 + quad*4];

  #pragma unroll
  for (int mi = 0; mi < 4; mi++){
    long r = arow0 + wm + mi*16 + l16;
    #pragma unroll
    for (int ni = 0; ni < 4; ni++){
      long c0 = brow0 + wn + ni*16 + quad*4;
      float4v v = acc[mi][ni] + bias4[ni];
      #pragma unroll
      for (int e = 0; e < 4; e++) v[e] = gelu_f(v[e]);
      uint2v pp;
      pp[0] = pack_bf2(v[0], v[1]);
      pp[1] = pack_bf2(v[2], v[3]);
      *(uint2v*)&Cout[r * N + c0] = pp;
    }
  }
}

// ---------------- mlp2 GEMM: Fout[nat(r)*192+c..] = Xres[..] + acc+bias (float4 RMW) ----------
__global__ __launch_bounds__(256) void gemm_rmw_kernel(const unsigned short* __restrict__ A,
                                                       const unsigned short* __restrict__ Bt,
                                                       const float* __restrict__ bias,
                                                       float* __restrict__ Fout,
                                                       const float* __restrict__ Xres,
                                                       int K){
  __shared__ unsigned short As[128 * 64];
  __shared__ unsigned short Bs[64 * 64];
  int tid = threadIdx.x;
  int wave = tid >> 6, lane = tid & 63, quad = lane >> 4, l16 = lane & 15;
  int wm = (wave >> 1) * 64, wn = (wave & 1) * 32;
  int lrow = lane >> 3, lg = lane & 7;
  int gcol = (lg ^ lrow) * 8;
  float4v acc[4][2];
  #pragma unroll
  for (int i = 0; i < 4; i++)
    #pragma unroll
    for (int jj = 0; jj < 2; jj++) acc[i][jj] = (float4v)0.f;

  long arow0 = (long)blockIdx.x * 128;
  long brow0 = (long)blockIdx.y * 64;
  int sw = (l16 & 7);

  for (int k0 = 0; k0 < K; k0 += 64){
    #pragma unroll
    for (int t = 0; t < 4; t++){
      int ci = wave + 4 * t;
      gload_lds16(&A[(arow0 + ci * 8 + lrow) * (long)K + k0 + gcol], &As[ci * 512]);
    }
    #pragma unroll
    for (int t = 0; t < 2; t++){
      int ci = wave + 4 * t;
      gload_lds16(&Bt[(brow0 + ci * 8 + lrow) * (long)K + k0 + gcol], &Bs[ci * 512]);
    }
    __syncthreads();
    #pragma unroll
    for (int kk8 = 0; kk8 < 8; kk8 += 4){
      short8 a[4], b[2];
      #pragma unroll
      for (int mi = 0; mi < 4; mi++)
        a[mi] = *(const short8*)&As[(wm + mi*16 + l16) * 64 + ((quad + kk8) ^ sw) * 8];
      #pragma unroll
      for (int ni = 0; ni < 2; ni++)
        b[ni] = *(const short8*)&Bs[(wn + ni*16 + l16) * 64 + ((quad + kk8) ^ sw) * 8];
      #pragma unroll
      for (int mi = 0; mi < 4; mi++)
        #pragma unroll
        for (int ni = 0; ni < 2; ni++)
          acc[mi][ni] = __builtin_amdgcn_mfma_f32_16x16x32_bf16(b[ni], a[mi], acc[mi][ni], 0, 0, 0);
    }
    __syncthreads();
  }

  float4v bias4[2];
  #pragma unroll
  for (int ni = 0; ni < 2; ni++)
    bias4[ni] = *(const float4v*)&bias[brow0 + wn + ni*16 + quad*4];

  #pragma unroll
  for (int mi = 0; mi < 4; mi++){
    long r = arow0 + wm + mi*16 + l16;
    long tr = (long)nat_token((int)r);
    #pragma unroll
    for (int ni = 0; ni < 2; ni++){
      long c0 = brow0 + wn + ni*16 + quad*4;
      long idx = tr * C_DIM + c0;
      float4v xr = *(const float4v*)&Xres[idx];
      *(float4v*)&Fout[idx] = xr + acc[mi][ni] + bias4[ni];
    }
  }
}

extern "C" void kernel_launch(void* const* d_in, const int* in_sizes, int n_in,
                              void* d_out, int out_size, void* d_ws, size_t ws_size,
                              hipStream_t stream){
  const float* x      = (const float*)d_in[0];
  const float* ln1_w  = (const float*)d_in[1];
  const float* ln1_b  = (const float*)d_in[2];
  const float* qkv_w  = (const float*)d_in[3];
  const float* qkv_b  = (const float*)d_in[4];
  const float* proj_w = (const float*)d_in[5];
  const float* proj_b = (const float*)d_in[6];
  const float* ln2_w  = (const float*)d_in[7];
  const float* ln2_b  = (const float*)d_in[8];
  const float* mlp_w1 = (const float*)d_in[9];
  const float* mlp_b1 = (const float*)d_in[10];
  const float* mlp_w2 = (const float*)d_in[11];
  const float* mlp_b2 = (const float*)d_in[12];
  float* out = (float*)d_out;   // fp32 output; hosts fp32 residual y between proj and mlp2

  // --- aliased workspace, all internal buffers bf16 ---
  char* ws = (char*)d_ws;
  unsigned short* qkv_wt = (unsigned short*)(ws);               // [576][192]
  unsigned short* proj_wt= (unsigned short*)(ws + 221184);      // [192][192]
  unsigned short* w1t    = (unsigned short*)(ws + 294912);      // [768][192]
  unsigned short* w2t    = (unsigned short*)(ws + 589824);      // [192][768]
  unsigned short* R1     = (unsigned short*)(ws + 884736);      // 50176x192 bf16
  unsigned short* R0     = (unsigned short*)(ws + 20152320);    // up to 50176x768 bf16

  unsigned short* xw   = R1;    // LN1'd, window layout
  unsigned short* hn   = R1;    // LN2'd, window layout (xw dead by then)
  unsigned short* obuf = R0;    // attention output, window layout (NOT aliased with xw)
  unsigned short* hbuf = R0;    // gelu(h), window layout (obuf dead by then)

  transpose_kernel<<<(110592 + 255) / 256, 256, 0, stream>>>(qkv_w, qkv_wt, 192, 576);
  transpose_kernel<<<(36864  + 255) / 256, 256, 0, stream>>>(proj_w, proj_wt, 192, 192);
  transpose_kernel<<<(147456 + 255) / 256, 256, 0, stream>>>(mlp_w1, w1t, 192, 768);
  transpose_kernel<<<(147456 + 255) / 256, 256, 0, stream>>>(mlp_w2, w2t, 768, 192);

  ln1_kernel<<<NTOK / 4, 256, 0, stream>>>(x, ln1_w, ln1_b, xw);
  win_attn_kernel<<<NTOK / 49, 768, 0, stream>>>(xw, qkv_wt, qkv_b, obuf);
  proj_ln2_kernel<<<NTOK / 64, 512, 0, stream>>>(obuf, proj_wt, proj_b, x, out, ln2_w, ln2_b, hn);
  gemm128_kernel<<<dim3(392, 6), 256, 0, stream>>>(hn, w1t, mlp_b1, hbuf, 768, 192);
  gemm_rmw_kernel<<<dim3(392, 3), 256, 0, stream>>>(hbuf, w2t, mlp_b2, out, out, 768);
}